// Round 14
// baseline (455.754 us; speedup 1.0000x reference)
//
#include <hip/hip_runtime.h>
#include <cstdint>
#include <cstddef>

#define DEV __device__ __forceinline__

typedef unsigned short u16;
typedef short short8 __attribute__((ext_vector_type(8)));
typedef float floatx4 __attribute__((ext_vector_type(4)));

constexpr int BB = 32;          // batch
constexpr int TT = 4096;        // seq
constexpr int RR = BB * TT;     // 131072 rows
constexpr int CH = 64;          // chunks per sequence
constexpr int LC = TT / CH;     // 64 steps per chunk

// workspace layout (bytes)
constexpr size_t OFF_LAM  = 0;                                   // float2[256]
constexpr size_t OFF_LAML = 2048;                                // float2[256]
constexpr size_t OFF_GAM  = 4096;                                // float[256]
constexpr size_t OFF_B1   = 8192;                                // u16[512*256]  (B_re;B_im)
constexpr size_t OFF_B2   = OFF_B1 + (size_t)512 * 256 * 2;      // u16[256*768]  (C_re|-C_im|Dm)
constexpr size_t OFF_B3   = OFF_B2 + (size_t)256 * 768 * 2;      // u16[512*256]  (Wl;Wr)
constexpr size_t OFF_BIG  = 2ull << 20;                          // 2MB
constexpr size_t SZB      = (size_t)RR * 256 * 2;                // 64MB per bf16 [R,256] buffer
// u @ OFF_BIG ; skip @ +1*SZB ; bure @ +2*SZB ; buim @ +3*SZB ; y @ +4*SZB ; carry @ +5*SZB (4MB)

DEV float bf2f(u16 u) {
    unsigned int i = ((unsigned int)u) << 16;
    float f;
    __builtin_memcpy(&f, &i, 4);
    return f;
}
DEV u16 f2bf(float f) {
    unsigned int i;
    __builtin_memcpy(&i, &f, 4);
    i += 0x7fffu + ((i >> 16) & 1u);   // RNE
    return (u16)(i >> 16);
}

DEV void gload16(const void* g, void* l) {
    __builtin_amdgcn_global_load_lds(
        (const __attribute__((address_space(1))) unsigned int*)g,
        (__attribute__((address_space(3))) unsigned int*)l, 16, 0, 0);
}

// ---------------------------------------------------------------- K0: setup
__global__ __launch_bounds__(256)
void k_setup(const float* __restrict__ nu_log, const float* __restrict__ theta_log,
             const float* __restrict__ gamma_log,
             const float* __restrict__ B_re, const float* __restrict__ B_im,
             const float* __restrict__ C_re, const float* __restrict__ C_im,
             const float* __restrict__ Dm,
             const float* __restrict__ Wl, const float* __restrict__ Wr,
             char* __restrict__ ws)
{
    float2* lam  = (float2*)(ws + OFF_LAM);
    float2* lamL = (float2*)(ws + OFF_LAML);
    float*  gam  = (float*)(ws + OFF_GAM);
    u16* B1 = (u16*)(ws + OFF_B1);
    u16* B2 = (u16*)(ws + OFF_B2);
    u16* B3 = (u16*)(ws + OFF_B3);
    int g = blockIdx.x * 256 + threadIdx.x;
    int stride = gridDim.x * 256;
    if (g < 256) {
        float mod = expf(-expf(nu_log[g]));
        float th  = expf(theta_log[g]);
        float lr = mod * cosf(th), li = mod * sinf(th);
        lam[g] = make_float2(lr, li);
        gam[g] = expf(gamma_log[g]);
        float pr = 1.f, pi = 0.f;
        for (int i = 0; i < LC; i++) { float nr = pr*lr - pi*li; pi = pr*li + pi*lr; pr = nr; }
        lamL[g] = make_float2(pr, pi);
    }
    for (int i = g; i < 512*256; i += stride) {
        int n = i >> 8, d = i & 255;
        B1[i] = f2bf(n < 256 ? B_re[n*256 + d] : B_im[(n-256)*256 + d]);
    }
    for (int i = g; i < 256*768; i += stride) {
        int m = i / 768, k = i - m*768;
        float v = (k < 256) ? C_re[m*256 + k]
                : (k < 512) ? -C_im[m*256 + (k-256)]
                            : Dm[m*256 + (k-512)];
        B2[i] = f2bf(v);
    }
    for (int i = g; i < 512*256; i += stride) {
        int n = i >> 8, d = i & 255;
        B3[i] = f2bf(n < 256 ? Wl[n*256 + d] : Wr[(n-256)*256 + d]);
    }
}

// ---------------------------------------------------------------- K1: LN1 + leaky
__global__ __launch_bounds__(256)
void k_ln1(const float* __restrict__ x, const float* __restrict__ w, const float* __restrict__ b,
           u16* __restrict__ u, u16* __restrict__ skip)
{
    const int wv = threadIdx.x >> 6, lane = threadIdx.x & 63;
    const size_t row = (size_t)blockIdx.x * 4 + wv;
    float4 v = ((const float4*)(x + row * 256))[lane];
    float s = v.x + v.y + v.z + v.w;
    float q = v.x*v.x + v.y*v.y + v.z*v.z + v.w*v.w;
    #pragma unroll
    for (int o = 32; o; o >>= 1) { s += __shfl_xor(s, o); q += __shfl_xor(q, o); }
    const float m  = s * (1.f/256.f);
    const float rs = rsqrtf(q * (1.f/256.f) - m*m + 1e-5f);
    const float4 wv4 = ((const float4*)w)[lane];
    const float4 bv4 = ((const float4*)b)[lane];
    float y0 = (v.x - m) * rs * wv4.x + bv4.x;
    float y1 = (v.y - m) * rs * wv4.y + bv4.y;
    float y2 = (v.z - m) * rs * wv4.z + bv4.z;
    float y3 = (v.w - m) * rs * wv4.w + bv4.w;
    ((ushort4*)(skip + row * 256))[lane] = make_ushort4(f2bf(y0), f2bf(y1), f2bf(y2), f2bf(y3));
    float u0 = y0 >= 0.f ? y0 : 0.01f * y0;
    float u1 = y1 >= 0.f ? y1 : 0.01f * y1;
    float u2 = y2 >= 0.f ? y2 : 0.01f * y2;
    float u3 = y3 >= 0.f ? y3 : 0.01f * y3;
    ((ushort4*)(u + row * 256))[lane] = make_ushort4(f2bf(u0), f2bf(u1), f2bf(u2), f2bf(u3));
}

// ---------------------------------------------------------------- GEMM1 (BK=64 dbuf, swizzled, T3 single-barrier)
// out = gam[n] * (u @ B1^T), split re/im by column.
__global__ __launch_bounds__(256)
void k_gemm1(const u16* __restrict__ A0, const u16* __restrict__ Bmat,
             u16* __restrict__ O0, u16* __restrict__ O1, const float* __restrict__ p0)
{
    __shared__ alignas(16) u16 As[2][128 * 64];
    __shared__ alignas(16) u16 Bs[2][128 * 64];
    const int wid = threadIdx.x >> 6, lane = threadIdx.x & 63;
    const int rowbase = blockIdx.x * 128;
    const int ct = blockIdx.y;
    const u16* Bbase = Bmat + (size_t)ct * 128 * 256;
    const int srow  = lane >> 3;
    const int sslot = (lane & 7) ^ srow;
    floatx4 acc[4][4] = {};

    auto stage = [&](int kt, int pb) {
        int kofs = kt * 64;
        #pragma unroll
        for (int i = 0; i < 4; i++) {
            int grp = wid * 4 + i;
            int row = grp * 8 + srow;
            gload16(A0 + (size_t)(rowbase + row) * 256 + kofs + sslot * 8,
                    (char*)&As[pb][0] + grp * 1024);
            gload16(Bbase + (size_t)row * 256 + kofs + sslot * 8,
                    (char*)&Bs[pb][0] + grp * 1024);
        }
    };

    stage(0, 0);
    asm volatile("s_waitcnt vmcnt(0)" ::: "memory");
    __builtin_amdgcn_s_barrier();
    const int wm = wid >> 1, wn = wid & 1;
    for (int kt = 0; kt < 4; ++kt) {
        const int pb = kt & 1;
        if (kt + 1 < 4) stage(kt + 1, pb ^ 1);     // loads fly under ds_read+MFMA
        short8 af[2][4], bfr[2][4];
        #pragma unroll
        for (int kk = 0; kk < 2; kk++) {
            const int rslot = (kk * 4 + (lane >> 4)) ^ (lane & 7);
            #pragma unroll
            for (int mi = 0; mi < 4; mi++)
                af[kk][mi] = *(const short8*)&As[pb][(wm*64 + mi*16 + (lane & 15)) * 64 + rslot * 8];
            #pragma unroll
            for (int ni = 0; ni < 4; ni++)
                bfr[kk][ni] = *(const short8*)&Bs[pb][(wn*64 + ni*16 + (lane & 15)) * 64 + rslot * 8];
        }
        #pragma unroll
        for (int mi = 0; mi < 4; mi++)
            #pragma unroll
            for (int ni = 0; ni < 4; ni++) {
                acc[mi][ni] = __builtin_amdgcn_mfma_f32_16x16x32_bf16(af[0][mi], bfr[0][ni], acc[mi][ni], 0, 0, 0);
                acc[mi][ni] = __builtin_amdgcn_mfma_f32_16x16x32_bf16(af[1][mi], bfr[1][ni], acc[mi][ni], 0, 0, 0);
            }
        asm volatile("s_waitcnt vmcnt(0)" ::: "memory");   // next tile fully landed
        __builtin_amdgcn_s_barrier();                      // single barrier per K-step
    }
    #pragma unroll
    for (int mi = 0; mi < 4; mi++) {
        #pragma unroll
        for (int ni = 0; ni < 4; ni++) {
            const int cc = wn*64 + ni*16 + (lane & 15);
            const int n  = ct * 128 + cc;
            u16* outp = (n < 256) ? O0 : O1;
            const int col = n & 255;
            const float scale = p0[col];
            #pragma unroll
            for (int r = 0; r < 4; r++) {
                const int row = rowbase + wm*64 + mi*16 + ((lane >> 4) << 2) + r;
                outp[(size_t)row * 256 + col] = f2bf(acc[mi][ni][r] * scale);
            }
        }
    }
}

// ---------------------------------------------------------------- GEMM3 (T3 single-barrier)
// gl/gr = y @ [Wl;Wr]^T + bias, split by column half.
__global__ __launch_bounds__(256)
void k_gemm3(const u16* __restrict__ A0, const u16* __restrict__ Bmat,
             u16* __restrict__ O0, u16* __restrict__ O1,
             const float* __restrict__ p0, const float* __restrict__ p1)
{
    __shared__ alignas(16) u16 As[2][128 * 64];
    __shared__ alignas(16) u16 Bs[2][128 * 64];
    const int wid = threadIdx.x >> 6, lane = threadIdx.x & 63;
    const int rowbase = blockIdx.x * 128;
    const int ct = blockIdx.y;
    const u16* Bbase = Bmat + (size_t)ct * 128 * 256;
    const int srow  = lane >> 3;
    const int sslot = (lane & 7) ^ srow;
    floatx4 acc[4][4] = {};

    auto stage = [&](int kt, int pb) {
        int kofs = kt * 64;
        #pragma unroll
        for (int i = 0; i < 4; i++) {
            int grp = wid * 4 + i;
            int row = grp * 8 + srow;
            gload16(A0 + (size_t)(rowbase + row) * 256 + kofs + sslot * 8,
                    (char*)&As[pb][0] + grp * 1024);
            gload16(Bbase + (size_t)row * 256 + kofs + sslot * 8,
                    (char*)&Bs[pb][0] + grp * 1024);
        }
    };

    stage(0, 0);
    asm volatile("s_waitcnt vmcnt(0)" ::: "memory");
    __builtin_amdgcn_s_barrier();
    const int wm = wid >> 1, wn = wid & 1;
    for (int kt = 0; kt < 4; ++kt) {
        const int pb = kt & 1;
        if (kt + 1 < 4) stage(kt + 1, pb ^ 1);
        short8 af[2][4], bfr[2][4];
        #pragma unroll
        for (int kk = 0; kk < 2; kk++) {
            const int rslot = (kk * 4 + (lane >> 4)) ^ (lane & 7);
            #pragma unroll
            for (int mi = 0; mi < 4; mi++)
                af[kk][mi] = *(const short8*)&As[pb][(wm*64 + mi*16 + (lane & 15)) * 64 + rslot * 8];
            #pragma unroll
            for (int ni = 0; ni < 4; ni++)
                bfr[kk][ni] = *(const short8*)&Bs[pb][(wn*64 + ni*16 + (lane & 15)) * 64 + rslot * 8];
        }
        #pragma unroll
        for (int mi = 0; mi < 4; mi++)
            #pragma unroll
            for (int ni = 0; ni < 4; ni++) {
                acc[mi][ni] = __builtin_amdgcn_mfma_f32_16x16x32_bf16(af[0][mi], bfr[0][ni], acc[mi][ni], 0, 0, 0);
                acc[mi][ni] = __builtin_amdgcn_mfma_f32_16x16x32_bf16(af[1][mi], bfr[1][ni], acc[mi][ni], 0, 0, 0);
            }
        asm volatile("s_waitcnt vmcnt(0)" ::: "memory");
        __builtin_amdgcn_s_barrier();
    }
    #pragma unroll
    for (int mi = 0; mi < 4; mi++) {
        #pragma unroll
        for (int ni = 0; ni < 4; ni++) {
            const int cc = wn*64 + ni*16 + (lane & 15);
            const int n  = ct * 128 + cc;
            u16* outp = (n < 256) ? O0 : O1;
            const int col = n & 255;
            const float badd = (n < 256 ? p0 : p1)[col];
            #pragma unroll
            for (int r = 0; r < 4; r++) {
                const int row = rowbase + wm*64 + mi*16 + ((lane >> 4) << 2) + r;
                outp[(size_t)row * 256 + col] = f2bf(acc[mi][ni][r] + badd);
            }
        }
    }
}

// ---------------------------------------------------------------- GEMM2 v5: fused LN2+leaky, BK=64 swizzled dbuf,
// T3 single-barrier. y = leaky(LN2([hr|hi|u] @ B2^T)); 128x256 tile, 512 thr (8 waves 2x4), NKT=12
__global__ __launch_bounds__(512)
void k_gemm2(const u16* __restrict__ Ahr, const u16* __restrict__ Ahi, const u16* __restrict__ Au,
             const u16* __restrict__ Bm, u16* __restrict__ Oy,
             const float* __restrict__ w2, const float* __restrict__ b2)
{
    __shared__ alignas(16) u16 As[2][128 * 64];   // 32 KB
    __shared__ alignas(16) u16 Bs[2][256 * 64];   // 64 KB
    __shared__ float st[8 * 64 * 2];              // 4 KB
    const int tid = threadIdx.x, wid = tid >> 6, lane = tid & 63;
    const int lanelo = lane & 15, lanehi = lane >> 4;
    const int rowbase = blockIdx.x * 128;
    const int wm = wid >> 2, wn = wid & 3;        // 2 x 4 waves: 64-row x 64-col each
    const int srow  = lane >> 3;
    const int sslot = (lane & 7) ^ srow;
    floatx4 acc[4][4] = {};

    auto stage = [&](int kt, int pb) {
        const u16* Asrc = (kt < 4) ? Ahr : (kt < 8) ? Ahi : Au;
        const int kofs = (kt & 3) * 64;
        #pragma unroll
        for (int i = 0; i < 2; i++) {             // A: 16 grps of 8 rows, 2 per wave
            int grp = wid * 2 + i;
            int row = grp * 8 + srow;
            gload16(Asrc + (size_t)(rowbase + row) * 256 + kofs + sslot * 8,
                    (char*)&As[pb][0] + grp * 1024);
        }
        #pragma unroll
        for (int i = 0; i < 4; i++) {             // B: 32 grps of 8 rows, 4 per wave
            int grp = wid * 4 + i;
            int row = grp * 8 + srow;
            gload16(Bm + (size_t)row * 768 + kt * 64 + sslot * 8,
                    (char*)&Bs[pb][0] + grp * 1024);
        }
    };

    stage(0, 0);
    asm volatile("s_waitcnt vmcnt(0)" ::: "memory");
    __builtin_amdgcn_s_barrier();
    for (int kt = 0; kt < 12; ++kt) {
        const int pb = kt & 1;
        if (kt + 1 < 12) stage(kt + 1, pb ^ 1);
        short8 af[2][4], bfr[2][4];
        #pragma unroll
        for (int kk = 0; kk < 2; kk++) {
            const int rslot = (kk * 4 + lanehi) ^ (lane & 7);
            #pragma unroll
            for (int mi = 0; mi < 4; mi++)
                af[kk][mi] = *(const short8*)&As[pb][(wm*64 + mi*16 + lanelo) * 64 + rslot * 8];
            #pragma unroll
            for (int ni = 0; ni < 4; ni++)
                bfr[kk][ni] = *(const short8*)&Bs[pb][(wn*64 + ni*16 + lanelo) * 64 + rslot * 8];
        }
        #pragma unroll
        for (int mi = 0; mi < 4; mi++)
            #pragma unroll
            for (int ni = 0; ni < 4; ni++) {
                acc[mi][ni] = __builtin_amdgcn_mfma_f32_16x16x32_bf16(af[0][mi], bfr[0][ni], acc[mi][ni], 0, 0, 0);
                acc[mi][ni] = __builtin_amdgcn_mfma_f32_16x16x32_bf16(af[1][mi], bfr[1][ni], acc[mi][ni], 0, 0, 0);
            }
        asm volatile("s_waitcnt vmcnt(0)" ::: "memory");
        __builtin_amdgcn_s_barrier();
    }

    // ---- fused LN2 + leaky epilogue ----
    float sarr[4][4], qarr[4][4];
    #pragma unroll
    for (int mi = 0; mi < 4; mi++)
        #pragma unroll
        for (int r = 0; r < 4; r++) {
            float s = 0.f, q = 0.f;
            #pragma unroll
            for (int ni = 0; ni < 4; ni++) { float v = acc[mi][ni][r]; s += v; q += v*v; }
            sarr[mi][r] = s; qarr[mi][r] = q;
        }
    #pragma unroll
    for (int o = 1; o < 16; o <<= 1)
        #pragma unroll
        for (int mi = 0; mi < 4; mi++)
            #pragma unroll
            for (int r = 0; r < 4; r++) {
                sarr[mi][r] += __shfl_xor(sarr[mi][r], o);
                qarr[mi][r] += __shfl_xor(qarr[mi][r], o);
            }
    if (lanelo == 0) {
        #pragma unroll
        for (int mi = 0; mi < 4; mi++)
            #pragma unroll
            for (int r = 0; r < 4; r++) {
                int rw = mi*16 + lanehi*4 + r;
                st[(wid*64 + rw)*2 + 0] = sarr[mi][r];
                st[(wid*64 + rw)*2 + 1] = qarr[mi][r];
            }
    }
    __syncthreads();
    float wc[4], bc[4];
    #pragma unroll
    for (int ni = 0; ni < 4; ni++) {
        int col = wn*64 + ni*16 + lanelo;
        wc[ni] = w2[col]; bc[ni] = b2[col];
    }
    #pragma unroll
    for (int mi = 0; mi < 4; mi++)
        #pragma unroll
        for (int r = 0; r < 4; r++) {
            const int rw = mi*16 + lanehi*4 + r;
            float S = 0.f, Q = 0.f;
            #pragma unroll
            for (int ww = 0; ww < 4; ww++) {
                S += st[((wm*4 + ww)*64 + rw)*2 + 0];
                Q += st[((wm*4 + ww)*64 + rw)*2 + 1];
            }
            const float m  = S * (1.f/256.f);
            const float rs = rsqrtf(Q * (1.f/256.f) - m*m + 1e-5f);
            const size_t row = (size_t)rowbase + wm*64 + rw;
            #pragma unroll
            for (int ni = 0; ni < 4; ni++) {
                int col = wn*64 + ni*16 + lanelo;
                float v = (acc[mi][ni][r] - m) * rs * wc[ni] + bc[ni];
                v = v >= 0.f ? v : 0.01f * v;
                Oy[row * 256 + col] = f2bf(v);
            }
        }
}

// ---------------------------------------------------------------- final: LN(gl)*LN(gr) -> LN4 -> + skip
__global__ __launch_bounds__(256)
void k_final(const u16* __restrict__ gl, const u16* __restrict__ gr, const u16* __restrict__ skip,
             const float* __restrict__ w4, const float* __restrict__ b4, float* __restrict__ out)
{
    const int wv = threadIdx.x >> 6, lane = threadIdx.x & 63;
    const size_t row = (size_t)blockIdx.x * 4 + wv;
    ushort4 ra = ((const ushort4*)(gl + row * 256))[lane];
    ushort4 rc = ((const ushort4*)(gr + row * 256))[lane];
    float a0 = bf2f(ra.x), a1 = bf2f(ra.y), a2 = bf2f(ra.z), a3 = bf2f(ra.w);
    float c0 = bf2f(rc.x), c1 = bf2f(rc.y), c2 = bf2f(rc.z), c3 = bf2f(rc.w);
    float s1 = a0+a1+a2+a3, q1 = a0*a0+a1*a1+a2*a2+a3*a3;
    float s2 = c0+c1+c2+c3, q2 = c0*c0+c1*c1+c2*c2+c3*c3;
    #pragma unroll
    for (int o = 32; o; o >>= 1) {
        s1 += __shfl_xor(s1, o); q1 += __shfl_xor(q1, o);
        s2 += __shfl_xor(s2, o); q2 += __shfl_xor(q2, o);
    }
    const float m1 = s1*(1.f/256.f), rs1 = rsqrtf(q1*(1.f/256.f) - m1*m1 + 1e-5f);
    const float m2 = s2*(1.f/256.f), rs2 = rsqrtf(q2*(1.f/256.f) - m2*m2 + 1e-5f);
    float v0 = ((a0-m1)*rs1) * ((c0-m2)*rs2);
    float v1 = ((a1-m1)*rs1) * ((c1-m2)*rs2);
    float v2 = ((a2-m1)*rs1) * ((c2-m2)*rs2);
    float v3 = ((a3-m1)*rs1) * ((c3-m2)*rs2);
    float s3 = v0+v1+v2+v3, q3 = v0*v0+v1*v1+v2*v2+v3*v3;
    #pragma unroll
    for (int o = 32; o; o >>= 1) { s3 += __shfl_xor(s3, o); q3 += __shfl_xor(q3, o); }
    const float m3 = s3*(1.f/256.f), rs3 = rsqrtf(q3*(1.f/256.f) - m3*m3 + 1e-5f);
    const float4 wv4 = ((const float4*)w4)[lane];
    const float4 bv4 = ((const float4*)b4)[lane];
    ushort4 sk = ((const ushort4*)(skip + row * 256))[lane];
    float o0 = (v0-m3)*rs3*wv4.x + bv4.x + bf2f(sk.x);
    float o1 = (v1-m3)*rs3*wv4.y + bv4.y + bf2f(sk.y);
    float o2 = (v2-m3)*rs3*wv4.z + bv4.z + bf2f(sk.z);
    float o3 = (v3-m3)*rs3*wv4.w + bv4.w + bf2f(sk.w);
    ((float4*)(out + row * 256))[lane] = make_float4(o0, o1, o2, o3);
}

// ---------------------------------------------------------------- scan: pass1 (local carries)
__global__ __launch_bounds__(128)
void k_scan1(const u16* __restrict__ bre, const u16* __restrict__ bim,
             float4* __restrict__ carry, const char* __restrict__ ws)
{
    const float2* lam = (const float2*)(ws + OFF_LAM);
    const int b = blockIdx.x, c = blockIdx.y, p = threadIdx.x;
    const unsigned int* pre = (const unsigned int*)bre;
    const unsigned int* pim = (const unsigned int*)bim;
    const float2 l0 = lam[2*p], l1 = lam[2*p + 1];
    float hr0 = 0, hi0 = 0, hr1 = 0, hi1 = 0;
    size_t base = ((size_t)b * TT + (size_t)c * LC) * 128 + p;
    #pragma unroll 8
    for (int j = 0; j < LC; j++) {
        unsigned int re = pre[base + (size_t)j * 128];
        unsigned int im = pim[base + (size_t)j * 128];
        float br0 = bf2f((u16)(re & 0xffff)), br1 = bf2f((u16)(re >> 16));
        float bi0 = bf2f((u16)(im & 0xffff)), bi1 = bf2f((u16)(im >> 16));
        float nr0 = fmaf(l0.x, hr0, fmaf(-l0.y, hi0, br0));
        float ni0 = fmaf(l0.x, hi0, fmaf( l0.y, hr0, bi0));
        float nr1 = fmaf(l1.x, hr1, fmaf(-l1.y, hi1, br1));
        float ni1 = fmaf(l1.x, hi1, fmaf( l1.y, hr1, bi1));
        hr0 = nr0; hi0 = ni0; hr1 = nr1; hi1 = ni1;
    }
    carry[((size_t)b * CH + c) * 128 + p] = make_float4(hr0, hi0, hr1, hi1);
}

// ---------------------------------------------------------------- scan: combine (exclusive prefix)
__global__ __launch_bounds__(128)
void k_comb(float4* __restrict__ carry, const char* __restrict__ ws)
{
    const float2* lamL = (const float2*)(ws + OFF_LAML);
    const int b = blockIdx.x, p = threadIdx.x;
    const float2 L0 = lamL[2*p], L1 = lamL[2*p + 1];
    float4 prev = make_float4(0.f, 0.f, 0.f, 0.f);
    size_t base = (size_t)b * CH * 128 + p;
    float4 nxt = carry[base];
    for (int c = 0; c < CH; c++) {
        float4 cur = nxt;
        if (c + 1 < CH) nxt = carry[base + (size_t)(c + 1) * 128];
        carry[base + (size_t)c * 128] = prev;
        float nx = fmaf(L0.x, prev.x, fmaf(-L0.y, prev.y, cur.x));
        float ny = fmaf(L0.x, prev.y, fmaf( L0.y, prev.x, cur.y));
        float nz = fmaf(L1.x, prev.z, fmaf(-L1.y, prev.w, cur.z));
        float nw = fmaf(L1.x, prev.w, fmaf( L1.y, prev.z, cur.w));
        prev = make_float4(nx, ny, nz, nw);
    }
}

// ---------------------------------------------------------------- scan: pass2 (finalize, in-place h over bu)
__global__ __launch_bounds__(128)
void k_scan2(u16* __restrict__ bre, u16* __restrict__ bim,
             const float4* __restrict__ carry, const char* __restrict__ ws)
{
    const float2* lam = (const float2*)(ws + OFF_LAM);
    const int b = blockIdx.x, c = blockIdx.y, p = threadIdx.x;
    unsigned int* pre = (unsigned int*)bre;
    unsigned int* pim = (unsigned int*)bim;
    const float2 l0 = lam[2*p], l1 = lam[2*p + 1];
    float4 h0 = carry[((size_t)b * CH + c) * 128 + p];
    float hr0 = h0.x, hi0 = h0.y, hr1 = h0.z, hi1 = h0.w;
    size_t base = ((size_t)b * TT + (size_t)c * LC) * 128 + p;
    #pragma unroll 8
    for (int j = 0; j < LC; j++) {
        size_t idx = base + (size_t)j * 128;
        unsigned int re = pre[idx];
        unsigned int im = pim[idx];
        float br0 = bf2f((u16)(re & 0xffff)), br1 = bf2f((u16)(re >> 16));
        float bi0 = bf2f((u16)(im & 0xffff)), bi1 = bf2f((u16)(im >> 16));
        float nr0 = fmaf(l0.x, hr0, fmaf(-l0.y, hi0, br0));
        float ni0 = fmaf(l0.x, hi0, fmaf( l0.y, hr0, bi0));
        float nr1 = fmaf(l1.x, hr1, fmaf(-l1.y, hi1, br1));
        float ni1 = fmaf(l1.x, hi1, fmaf( l1.y, hr1, bi1));
        hr0 = nr0; hi0 = ni0; hr1 = nr1; hi1 = ni1;
        pre[idx] = ((unsigned int)f2bf(hr1) << 16) | f2bf(hr0);
        pim[idx] = ((unsigned int)f2bf(hi1) << 16) | f2bf(hi0);
    }
}

// ---------------------------------------------------------------- launch
extern "C" void kernel_launch(void* const* d_in, const int* in_sizes, int n_in,
                              void* d_out, int out_size, void* d_ws, size_t ws_size,
                              hipStream_t stream)
{
    (void)in_sizes; (void)n_in; (void)out_size; (void)ws_size;
    const float* x         = (const float*)d_in[0];
    const float* ln1_w     = (const float*)d_in[1];
    const float* ln1_b     = (const float*)d_in[2];
    const float* nu_log    = (const float*)d_in[3];
    const float* theta_log = (const float*)d_in[4];
    const float* gamma_log = (const float*)d_in[5];
    const float* B_re      = (const float*)d_in[6];
    const float* B_im      = (const float*)d_in[7];
    const float* C_re      = (const float*)d_in[8];
    const float* C_im      = (const float*)d_in[9];
    const float* Dm        = (const float*)d_in[10];
    const float* ln2_w     = (const float*)d_in[11];
    const float* ln2_b     = (const float*)d_in[12];
    const float* Wl        = (const float*)d_in[13];
    const float* bl        = (const float*)d_in[14];
    const float* Wr        = (const float*)d_in[15];
    const float* br        = (const float*)d_in[16];
    const float* ln4_w     = (const float*)d_in[17];
    const float* ln4_b     = (const float*)d_in[18];

    char* ws = (char*)d_ws;
    float* gam = (float*)(ws + OFF_GAM);
    u16* B1 = (u16*)(ws + OFF_B1);
    u16* B2 = (u16*)(ws + OFF_B2);
    u16* B3 = (u16*)(ws + OFF_B3);
    u16* u    = (u16*)(ws + OFF_BIG);
    u16* skip = (u16*)(ws + OFF_BIG + 1 * SZB);
    u16* bure = (u16*)(ws + OFF_BIG + 2 * SZB);
    u16* buim = (u16*)(ws + OFF_BIG + 3 * SZB);
    u16* y    = (u16*)(ws + OFF_BIG + 4 * SZB);
    float4* carry = (float4*)(ws + OFF_BIG + 5 * SZB);
    float* out = (float*)d_out;

    k_setup<<<dim3(256), dim3(256), 0, stream>>>(nu_log, theta_log, gamma_log,
                                                 B_re, B_im, C_re, C_im, Dm, Wl, Wr, ws);
    k_ln1<<<dim3(RR/4), dim3(256), 0, stream>>>(x, ln1_w, ln1_b, u, skip);
    k_gemm1<<<dim3(RR/128, 4), dim3(256), 0, stream>>>(u, B1, bure, buim, gam);
    k_scan1<<<dim3(BB, CH), dim3(128), 0, stream>>>(bure, buim, carry, ws);
    k_comb<<<dim3(BB), dim3(128), 0, stream>>>(carry, ws);
    k_scan2<<<dim3(BB, CH), dim3(128), 0, stream>>>(bure, buim, carry, ws);
    k_gemm2<<<dim3(RR/128), dim3(512), 0, stream>>>(bure, buim, u, B2, y, ln2_w, ln2_b);
    k_gemm3<<<dim3(RR/128, 4), dim3(256), 0, stream>>>(y, B3, bure, buim, bl, br);
    k_final<<<dim3(RR/4), dim3(256), 0, stream>>>(bure, buim, skip, ln4_w, ln4_b, out);
}

// Round 15
// 426.642 us; speedup vs baseline: 1.0682x; 1.0682x over previous
//
#include <hip/hip_runtime.h>
#include <cstdint>
#include <cstddef>

#define DEV __device__ __forceinline__

typedef unsigned short u16;
typedef short short8 __attribute__((ext_vector_type(8)));
typedef float floatx4 __attribute__((ext_vector_type(4)));

constexpr int BB = 32;          // batch
constexpr int TT = 4096;        // seq
constexpr int RR = BB * TT;     // 131072 rows
constexpr int CH = 64;          // chunks per sequence
constexpr int LC = TT / CH;     // 64 steps per chunk

// workspace layout (bytes)
constexpr size_t OFF_LAM  = 0;                                   // float2[256]
constexpr size_t OFF_LAML = 2048;                                // float2[256]
constexpr size_t OFF_GAM  = 4096;                                // float[256]
constexpr size_t OFF_B1   = 8192;                                // u16[512*256]  (B_re;B_im)
constexpr size_t OFF_B2   = OFF_B1 + (size_t)512 * 256 * 2;      // u16[256*768]  (C_re|-C_im|Dm)
constexpr size_t OFF_B3   = OFF_B2 + (size_t)256 * 768 * 2;      // u16[512*256]  (Wl;Wr)
constexpr size_t OFF_BIG  = 2ull << 20;                          // 2MB
constexpr size_t SZB      = (size_t)RR * 256 * 2;                // 64MB per bf16 [R,256] buffer
// u @ OFF_BIG ; skip @ +1*SZB ; bure @ +2*SZB ; buim @ +3*SZB ; y @ +4*SZB ; carry @ +5*SZB (4MB)

DEV float bf2f(u16 u) {
    unsigned int i = ((unsigned int)u) << 16;
    float f;
    __builtin_memcpy(&f, &i, 4);
    return f;
}
DEV u16 f2bf(float f) {
    unsigned int i;
    __builtin_memcpy(&i, &f, 4);
    i += 0x7fffu + ((i >> 16) & 1u);   // RNE
    return (u16)(i >> 16);
}

DEV void gload16(const void* g, void* l) {
    __builtin_amdgcn_global_load_lds(
        (const __attribute__((address_space(1))) unsigned int*)g,
        (__attribute__((address_space(3))) unsigned int*)l, 16, 0, 0);
}

// ---------------------------------------------------------------- K0: setup
__global__ __launch_bounds__(256)
void k_setup(const float* __restrict__ nu_log, const float* __restrict__ theta_log,
             const float* __restrict__ gamma_log,
             const float* __restrict__ B_re, const float* __restrict__ B_im,
             const float* __restrict__ C_re, const float* __restrict__ C_im,
             const float* __restrict__ Dm,
             const float* __restrict__ Wl, const float* __restrict__ Wr,
             char* __restrict__ ws)
{
    float2* lam  = (float2*)(ws + OFF_LAM);
    float2* lamL = (float2*)(ws + OFF_LAML);
    float*  gam  = (float*)(ws + OFF_GAM);
    u16* B1 = (u16*)(ws + OFF_B1);
    u16* B2 = (u16*)(ws + OFF_B2);
    u16* B3 = (u16*)(ws + OFF_B3);
    int g = blockIdx.x * 256 + threadIdx.x;
    int stride = gridDim.x * 256;
    if (g < 256) {
        float mod = expf(-expf(nu_log[g]));
        float th  = expf(theta_log[g]);
        float lr = mod * cosf(th), li = mod * sinf(th);
        lam[g] = make_float2(lr, li);
        gam[g] = expf(gamma_log[g]);
        float pr = 1.f, pi = 0.f;
        for (int i = 0; i < LC; i++) { float nr = pr*lr - pi*li; pi = pr*li + pi*lr; pr = nr; }
        lamL[g] = make_float2(pr, pi);
    }
    for (int i = g; i < 512*256; i += stride) {
        int n = i >> 8, d = i & 255;
        B1[i] = f2bf(n < 256 ? B_re[n*256 + d] : B_im[(n-256)*256 + d]);
    }
    for (int i = g; i < 256*768; i += stride) {
        int m = i / 768, k = i - m*768;
        float v = (k < 256) ? C_re[m*256 + k]
                : (k < 512) ? -C_im[m*256 + (k-256)]
                            : Dm[m*256 + (k-512)];
        B2[i] = f2bf(v);
    }
    for (int i = g; i < 512*256; i += stride) {
        int n = i >> 8, d = i & 255;
        B3[i] = f2bf(n < 256 ? Wl[n*256 + d] : Wr[(n-256)*256 + d]);
    }
}

// ---------------------------------------------------------------- K1: LN1 + leaky
__global__ __launch_bounds__(256)
void k_ln1(const float* __restrict__ x, const float* __restrict__ w, const float* __restrict__ b,
           u16* __restrict__ u, u16* __restrict__ skip)
{
    const int wv = threadIdx.x >> 6, lane = threadIdx.x & 63;
    const size_t row = (size_t)blockIdx.x * 4 + wv;
    float4 v = ((const float4*)(x + row * 256))[lane];
    float s = v.x + v.y + v.z + v.w;
    float q = v.x*v.x + v.y*v.y + v.z*v.z + v.w*v.w;
    #pragma unroll
    for (int o = 32; o; o >>= 1) { s += __shfl_xor(s, o); q += __shfl_xor(q, o); }
    const float m  = s * (1.f/256.f);
    const float rs = rsqrtf(q * (1.f/256.f) - m*m + 1e-5f);
    const float4 wv4 = ((const float4*)w)[lane];
    const float4 bv4 = ((const float4*)b)[lane];
    float y0 = (v.x - m) * rs * wv4.x + bv4.x;
    float y1 = (v.y - m) * rs * wv4.y + bv4.y;
    float y2 = (v.z - m) * rs * wv4.z + bv4.z;
    float y3 = (v.w - m) * rs * wv4.w + bv4.w;
    ((ushort4*)(skip + row * 256))[lane] = make_ushort4(f2bf(y0), f2bf(y1), f2bf(y2), f2bf(y3));
    float u0 = y0 >= 0.f ? y0 : 0.01f * y0;
    float u1 = y1 >= 0.f ? y1 : 0.01f * y1;
    float u2 = y2 >= 0.f ? y2 : 0.01f * y2;
    float u3 = y3 >= 0.f ? y3 : 0.01f * y3;
    ((ushort4*)(u + row * 256))[lane] = make_ushort4(f2bf(u0), f2bf(u1), f2bf(u2), f2bf(u3));
}

// ---------------------------------------------------------------- GEMM1 (BK=64 dbuf, swizzled)
// out = gam[n] * (u @ B1^T), split re/im by column.
__global__ __launch_bounds__(256)
void k_gemm1(const u16* __restrict__ A0, const u16* __restrict__ Bmat,
             u16* __restrict__ O0, u16* __restrict__ O1, const float* __restrict__ p0)
{
    __shared__ alignas(16) u16 As[2][128 * 64];
    __shared__ alignas(16) u16 Bs[2][128 * 64];
    const int wid = threadIdx.x >> 6, lane = threadIdx.x & 63;
    const int rowbase = blockIdx.x * 128;
    const int ct = blockIdx.y;
    const u16* Bbase = Bmat + (size_t)ct * 128 * 256;
    const int srow  = lane >> 3;
    const int sslot = (lane & 7) ^ srow;
    floatx4 acc[4][4] = {};

    auto stage = [&](int kt, int pb) {
        int kofs = kt * 64;
        #pragma unroll
        for (int i = 0; i < 4; i++) {
            int grp = wid * 4 + i;
            int row = grp * 8 + srow;
            gload16(A0 + (size_t)(rowbase + row) * 256 + kofs + sslot * 8,
                    (char*)&As[pb][0] + grp * 1024);
            gload16(Bbase + (size_t)row * 256 + kofs + sslot * 8,
                    (char*)&Bs[pb][0] + grp * 1024);
        }
    };

    stage(0, 0);
    const int wm = wid >> 1, wn = wid & 1;
    for (int kt = 0; kt < 4; ++kt) {
        const int pb = kt & 1;
        if (kt + 1 < 4) {
            stage(kt + 1, pb ^ 1);
            asm volatile("s_waitcnt vmcnt(8)" ::: "memory");
        } else {
            asm volatile("s_waitcnt vmcnt(0)" ::: "memory");
        }
        __builtin_amdgcn_s_barrier();
        short8 af[2][4], bfr[2][4];
        #pragma unroll
        for (int kk = 0; kk < 2; kk++) {
            const int rslot = (kk * 4 + (lane >> 4)) ^ (lane & 7);
            #pragma unroll
            for (int mi = 0; mi < 4; mi++)
                af[kk][mi] = *(const short8*)&As[pb][(wm*64 + mi*16 + (lane & 15)) * 64 + rslot * 8];
            #pragma unroll
            for (int ni = 0; ni < 4; ni++)
                bfr[kk][ni] = *(const short8*)&Bs[pb][(wn*64 + ni*16 + (lane & 15)) * 64 + rslot * 8];
        }
        #pragma unroll
        for (int mi = 0; mi < 4; mi++)
            #pragma unroll
            for (int ni = 0; ni < 4; ni++) {
                acc[mi][ni] = __builtin_amdgcn_mfma_f32_16x16x32_bf16(af[0][mi], bfr[0][ni], acc[mi][ni], 0, 0, 0);
                acc[mi][ni] = __builtin_amdgcn_mfma_f32_16x16x32_bf16(af[1][mi], bfr[1][ni], acc[mi][ni], 0, 0, 0);
            }
        __builtin_amdgcn_s_barrier();
    }
    #pragma unroll
    for (int mi = 0; mi < 4; mi++) {
        #pragma unroll
        for (int ni = 0; ni < 4; ni++) {
            const int cc = wn*64 + ni*16 + (lane & 15);
            const int n  = ct * 128 + cc;
            u16* outp = (n < 256) ? O0 : O1;
            const int col = n & 255;
            const float scale = p0[col];
            #pragma unroll
            for (int r = 0; r < 4; r++) {
                const int row = rowbase + wm*64 + mi*16 + ((lane >> 4) << 2) + r;
                outp[(size_t)row * 256 + col] = f2bf(acc[mi][ni][r] * scale);
            }
        }
    }
}

// ---------------------------------------------------------------- GEMM3 (round-4 proven structure)
// gl/gr = y @ [Wl;Wr]^T + bias, split by column half.
__global__ __launch_bounds__(256)
void k_gemm3(const u16* __restrict__ A0, const u16* __restrict__ Bmat,
             u16* __restrict__ O0, u16* __restrict__ O1,
             const float* __restrict__ p0, const float* __restrict__ p1)
{
    __shared__ alignas(16) u16 As[2][128 * 64];
    __shared__ alignas(16) u16 Bs[2][128 * 64];
    const int wid = threadIdx.x >> 6, lane = threadIdx.x & 63;
    const int rowbase = blockIdx.x * 128;
    const int ct = blockIdx.y;
    const u16* Bbase = Bmat + (size_t)ct * 128 * 256;
    const int srow  = lane >> 3;
    const int sslot = (lane & 7) ^ srow;
    floatx4 acc[4][4] = {};

    auto stage = [&](int kt, int pb) {
        int kofs = kt * 64;
        #pragma unroll
        for (int i = 0; i < 4; i++) {
            int grp = wid * 4 + i;
            int row = grp * 8 + srow;
            gload16(A0 + (size_t)(rowbase + row) * 256 + kofs + sslot * 8,
                    (char*)&As[pb][0] + grp * 1024);
            gload16(Bbase + (size_t)row * 256 + kofs + sslot * 8,
                    (char*)&Bs[pb][0] + grp * 1024);
        }
    };

    stage(0, 0);
    const int wm = wid >> 1, wn = wid & 1;
    for (int kt = 0; kt < 4; ++kt) {
        const int pb = kt & 1;
        if (kt + 1 < 4) {
            stage(kt + 1, pb ^ 1);
            asm volatile("s_waitcnt vmcnt(8)" ::: "memory");
        } else {
            asm volatile("s_waitcnt vmcnt(0)" ::: "memory");
        }
        __builtin_amdgcn_s_barrier();
        short8 af[2][4], bfr[2][4];
        #pragma unroll
        for (int kk = 0; kk < 2; kk++) {
            const int rslot = (kk * 4 + (lane >> 4)) ^ (lane & 7);
            #pragma unroll
            for (int mi = 0; mi < 4; mi++)
                af[kk][mi] = *(const short8*)&As[pb][(wm*64 + mi*16 + (lane & 15)) * 64 + rslot * 8];
            #pragma unroll
            for (int ni = 0; ni < 4; ni++)
                bfr[kk][ni] = *(const short8*)&Bs[pb][(wn*64 + ni*16 + (lane & 15)) * 64 + rslot * 8];
        }
        #pragma unroll
        for (int mi = 0; mi < 4; mi++)
            #pragma unroll
            for (int ni = 0; ni < 4; ni++) {
                acc[mi][ni] = __builtin_amdgcn_mfma_f32_16x16x32_bf16(af[0][mi], bfr[0][ni], acc[mi][ni], 0, 0, 0);
                acc[mi][ni] = __builtin_amdgcn_mfma_f32_16x16x32_bf16(af[1][mi], bfr[1][ni], acc[mi][ni], 0, 0, 0);
            }
        __builtin_amdgcn_s_barrier();
    }
    #pragma unroll
    for (int mi = 0; mi < 4; mi++) {
        #pragma unroll
        for (int ni = 0; ni < 4; ni++) {
            const int cc = wn*64 + ni*16 + (lane & 15);
            const int n  = ct * 128 + cc;
            u16* outp = (n < 256) ? O0 : O1;
            const int col = n & 255;
            const float badd = (n < 256 ? p0 : p1)[col];
            #pragma unroll
            for (int r = 0; r < 4; r++) {
                const int row = rowbase + wm*64 + mi*16 + ((lane >> 4) << 2) + r;
                outp[(size_t)row * 256 + col] = f2bf(acc[mi][ni][r] + badd);
            }
        }
    }
}

// ---------------------------------------------------------------- GEMM2 v3: fused LN2+leaky, BK=64 swizzled dbuf
// y = leaky(LN2([hr|hi|u] @ B2^T)); tile 128 rows x 256 cols (full N), 512 thr (8 waves 2x4), NKT=12
__global__ __launch_bounds__(512)
void k_gemm2(const u16* __restrict__ Ahr, const u16* __restrict__ Ahi, const u16* __restrict__ Au,
             const u16* __restrict__ Bm, u16* __restrict__ Oy,
             const float* __restrict__ w2, const float* __restrict__ b2)
{
    __shared__ alignas(16) u16 As[2][128 * 64];   // 32 KB
    __shared__ alignas(16) u16 Bs[2][256 * 64];   // 64 KB
    __shared__ float st[8 * 64 * 2];              // 4 KB
    const int tid = threadIdx.x, wid = tid >> 6, lane = tid & 63;
    const int lanelo = lane & 15, lanehi = lane >> 4;
    const int rowbase = blockIdx.x * 128;
    const int wm = wid >> 2, wn = wid & 3;        // 2 x 4 waves: 64-row x 64-col each
    const int srow  = lane >> 3;
    const int sslot = (lane & 7) ^ srow;
    floatx4 acc[4][4] = {};

    auto stage = [&](int kt, int pb) {
        const u16* Asrc = (kt < 4) ? Ahr : (kt < 8) ? Ahi : Au;
        const int kofs = (kt & 3) * 64;
        #pragma unroll
        for (int i = 0; i < 2; i++) {             // A: 16 grps of 8 rows, 2 per wave
            int grp = wid * 2 + i;
            int row = grp * 8 + srow;
            gload16(Asrc + (size_t)(rowbase + row) * 256 + kofs + sslot * 8,
                    (char*)&As[pb][0] + grp * 1024);
        }
        #pragma unroll
        for (int i = 0; i < 4; i++) {             // B: 32 grps of 8 rows, 4 per wave
            int grp = wid * 4 + i;
            int row = grp * 8 + srow;
            gload16(Bm + (size_t)row * 768 + kt * 64 + sslot * 8,
                    (char*)&Bs[pb][0] + grp * 1024);
        }
    };

    stage(0, 0);
    for (int kt = 0; kt < 12; ++kt) {
        const int pb = kt & 1;
        if (kt + 1 < 12) {
            stage(kt + 1, pb ^ 1);
            asm volatile("s_waitcnt vmcnt(6)" ::: "memory");   // tile kt's 6 loads landed; kt+1 in flight
        } else {
            asm volatile("s_waitcnt vmcnt(0)" ::: "memory");
        }
        __builtin_amdgcn_s_barrier();
        short8 af[2][4], bfr[2][4];
        #pragma unroll
        for (int kk = 0; kk < 2; kk++) {
            const int rslot = (kk * 4 + lanehi) ^ (lane & 7);
            #pragma unroll
            for (int mi = 0; mi < 4; mi++)
                af[kk][mi] = *(const short8*)&As[pb][(wm*64 + mi*16 + lanelo) * 64 + rslot * 8];
            #pragma unroll
            for (int ni = 0; ni < 4; ni++)
                bfr[kk][ni] = *(const short8*)&Bs[pb][(wn*64 + ni*16 + lanelo) * 64 + rslot * 8];
        }
        #pragma unroll
        for (int mi = 0; mi < 4; mi++)
            #pragma unroll
            for (int ni = 0; ni < 4; ni++) {
                acc[mi][ni] = __builtin_amdgcn_mfma_f32_16x16x32_bf16(af[0][mi], bfr[0][ni], acc[mi][ni], 0, 0, 0);
                acc[mi][ni] = __builtin_amdgcn_mfma_f32_16x16x32_bf16(af[1][mi], bfr[1][ni], acc[mi][ni], 0, 0, 0);
            }
        __builtin_amdgcn_s_barrier();
    }

    // ---- fused LN2 + leaky epilogue ----
    float sarr[4][4], qarr[4][4];
    #pragma unroll
    for (int mi = 0; mi < 4; mi++)
        #pragma unroll
        for (int r = 0; r < 4; r++) {
            float s = 0.f, q = 0.f;
            #pragma unroll
            for (int ni = 0; ni < 4; ni++) { float v = acc[mi][ni][r]; s += v; q += v*v; }
            sarr[mi][r] = s; qarr[mi][r] = q;
        }
    #pragma unroll
    for (int o = 1; o < 16; o <<= 1)
        #pragma unroll
        for (int mi = 0; mi < 4; mi++)
            #pragma unroll
            for (int r = 0; r < 4; r++) {
                sarr[mi][r] += __shfl_xor(sarr[mi][r], o);
                qarr[mi][r] += __shfl_xor(qarr[mi][r], o);
            }
    if (lanelo == 0) {
        #pragma unroll
        for (int mi = 0; mi < 4; mi++)
            #pragma unroll
            for (int r = 0; r < 4; r++) {
                int rw = mi*16 + lanehi*4 + r;
                st[(wid*64 + rw)*2 + 0] = sarr[mi][r];
                st[(wid*64 + rw)*2 + 1] = qarr[mi][r];
            }
    }
    __syncthreads();
    float wc[4], bc[4];
    #pragma unroll
    for (int ni = 0; ni < 4; ni++) {
        int col = wn*64 + ni*16 + lanelo;
        wc[ni] = w2[col]; bc[ni] = b2[col];
    }
    #pragma unroll
    for (int mi = 0; mi < 4; mi++)
        #pragma unroll
        for (int r = 0; r < 4; r++) {
            const int rw = mi*16 + lanehi*4 + r;
            float S = 0.f, Q = 0.f;
            #pragma unroll
            for (int ww = 0; ww < 4; ww++) {
                S += st[((wm*4 + ww)*64 + rw)*2 + 0];
                Q += st[((wm*4 + ww)*64 + rw)*2 + 1];
            }
            const float m  = S * (1.f/256.f);
            const float rs = rsqrtf(Q * (1.f/256.f) - m*m + 1e-5f);
            const size_t row = (size_t)rowbase + wm*64 + rw;
            #pragma unroll
            for (int ni = 0; ni < 4; ni++) {
                int col = wn*64 + ni*16 + lanelo;
                float v = (acc[mi][ni][r] - m) * rs * wc[ni] + bc[ni];
                v = v >= 0.f ? v : 0.01f * v;
                Oy[row * 256 + col] = f2bf(v);
            }
        }
}

// ---------------------------------------------------------------- final: LN(gl)*LN(gr) -> LN4 -> + skip
__global__ __launch_bounds__(256)
void k_final(const u16* __restrict__ gl, const u16* __restrict__ gr, const u16* __restrict__ skip,
             const float* __restrict__ w4, const float* __restrict__ b4, float* __restrict__ out)
{
    const int wv = threadIdx.x >> 6, lane = threadIdx.x & 63;
    const size_t row = (size_t)blockIdx.x * 4 + wv;
    ushort4 ra = ((const ushort4*)(gl + row * 256))[lane];
    ushort4 rc = ((const ushort4*)(gr + row * 256))[lane];
    float a0 = bf2f(ra.x), a1 = bf2f(ra.y), a2 = bf2f(ra.z), a3 = bf2f(ra.w);
    float c0 = bf2f(rc.x), c1 = bf2f(rc.y), c2 = bf2f(rc.z), c3 = bf2f(rc.w);
    float s1 = a0+a1+a2+a3, q1 = a0*a0+a1*a1+a2*a2+a3*a3;
    float s2 = c0+c1+c2+c3, q2 = c0*c0+c1*c1+c2*c2+c3*c3;
    #pragma unroll
    for (int o = 32; o; o >>= 1) {
        s1 += __shfl_xor(s1, o); q1 += __shfl_xor(q1, o);
        s2 += __shfl_xor(s2, o); q2 += __shfl_xor(q2, o);
    }
    const float m1 = s1*(1.f/256.f), rs1 = rsqrtf(q1*(1.f/256.f) - m1*m1 + 1e-5f);
    const float m2 = s2*(1.f/256.f), rs2 = rsqrtf(q2*(1.f/256.f) - m2*m2 + 1e-5f);
    float v0 = ((a0-m1)*rs1) * ((c0-m2)*rs2);
    float v1 = ((a1-m1)*rs1) * ((c1-m2)*rs2);
    float v2 = ((a2-m1)*rs1) * ((c2-m2)*rs2);
    float v3 = ((a3-m1)*rs1) * ((c3-m2)*rs2);
    float s3 = v0+v1+v2+v3, q3 = v0*v0+v1*v1+v2*v2+v3*v3;
    #pragma unroll
    for (int o = 32; o; o >>= 1) { s3 += __shfl_xor(s3, o); q3 += __shfl_xor(q3, o); }
    const float m3 = s3*(1.f/256.f), rs3 = rsqrtf(q3*(1.f/256.f) - m3*m3 + 1e-5f);
    const float4 wv4 = ((const float4*)w4)[lane];
    const float4 bv4 = ((const float4*)b4)[lane];
    ushort4 sk = ((const ushort4*)(skip + row * 256))[lane];
    float o0 = (v0-m3)*rs3*wv4.x + bv4.x + bf2f(sk.x);
    float o1 = (v1-m3)*rs3*wv4.y + bv4.y + bf2f(sk.y);
    float o2 = (v2-m3)*rs3*wv4.z + bv4.z + bf2f(sk.z);
    float o3 = (v3-m3)*rs3*wv4.w + bv4.w + bf2f(sk.w);
    ((float4*)(out + row * 256))[lane] = make_float4(o0, o1, o2, o3);
}

// ---------------------------------------------------------------- scan: pass1 (local carries)
__global__ __launch_bounds__(128)
void k_scan1(const u16* __restrict__ bre, const u16* __restrict__ bim,
             float4* __restrict__ carry, const char* __restrict__ ws)
{
    const float2* lam = (const float2*)(ws + OFF_LAM);
    const int b = blockIdx.x, c = blockIdx.y, p = threadIdx.x;
    const unsigned int* pre = (const unsigned int*)bre;
    const unsigned int* pim = (const unsigned int*)bim;
    const float2 l0 = lam[2*p], l1 = lam[2*p + 1];
    float hr0 = 0, hi0 = 0, hr1 = 0, hi1 = 0;
    size_t base = ((size_t)b * TT + (size_t)c * LC) * 128 + p;
    #pragma unroll 8
    for (int j = 0; j < LC; j++) {
        unsigned int re = pre[base + (size_t)j * 128];
        unsigned int im = pim[base + (size_t)j * 128];
        float br0 = bf2f((u16)(re & 0xffff)), br1 = bf2f((u16)(re >> 16));
        float bi0 = bf2f((u16)(im & 0xffff)), bi1 = bf2f((u16)(im >> 16));
        float nr0 = fmaf(l0.x, hr0, fmaf(-l0.y, hi0, br0));
        float ni0 = fmaf(l0.x, hi0, fmaf( l0.y, hr0, bi0));
        float nr1 = fmaf(l1.x, hr1, fmaf(-l1.y, hi1, br1));
        float ni1 = fmaf(l1.x, hi1, fmaf( l1.y, hr1, bi1));
        hr0 = nr0; hi0 = ni0; hr1 = nr1; hi1 = ni1;
    }
    carry[((size_t)b * CH + c) * 128 + p] = make_float4(hr0, hi0, hr1, hi1);
}

// ---------------------------------------------------------------- scan: combine (exclusive prefix)
__global__ __launch_bounds__(128)
void k_comb(float4* __restrict__ carry, const char* __restrict__ ws)
{
    const float2* lamL = (const float2*)(ws + OFF_LAML);
    const int b = blockIdx.x, p = threadIdx.x;
    const float2 L0 = lamL[2*p], L1 = lamL[2*p + 1];
    float4 prev = make_float4(0.f, 0.f, 0.f, 0.f);
    size_t base = (size_t)b * CH * 128 + p;
    float4 nxt = carry[base];
    for (int c = 0; c < CH; c++) {
        float4 cur = nxt;
        if (c + 1 < CH) nxt = carry[base + (size_t)(c + 1) * 128];
        carry[base + (size_t)c * 128] = prev;
        float nx = fmaf(L0.x, prev.x, fmaf(-L0.y, prev.y, cur.x));
        float ny = fmaf(L0.x, prev.y, fmaf( L0.y, prev.x, cur.y));
        float nz = fmaf(L1.x, prev.z, fmaf(-L1.y, prev.w, cur.z));
        float nw = fmaf(L1.x, prev.w, fmaf( L1.y, prev.z, cur.w));
        prev = make_float4(nx, ny, nz, nw);
    }
}

// ---------------------------------------------------------------- scan: pass2 (finalize, in-place h over bu)
__global__ __launch_bounds__(128)
void k_scan2(u16* __restrict__ bre, u16* __restrict__ bim,
             const float4* __restrict__ carry, const char* __restrict__ ws)
{
    const float2* lam = (const float2*)(ws + OFF_LAM);
    const int b = blockIdx.x, c = blockIdx.y, p = threadIdx.x;
    unsigned int* pre = (unsigned int*)bre;
    unsigned int* pim = (unsigned int*)bim;
    const float2 l0 = lam[2*p], l1 = lam[2*p + 1];
    float4 h0 = carry[((size_t)b * CH + c) * 128 + p];
    float hr0 = h0.x, hi0 = h0.y, hr1 = h0.z, hi1 = h0.w;
    size_t base = ((size_t)b * TT + (size_t)c * LC) * 128 + p;
    #pragma unroll 8
    for (int j = 0; j < LC; j++) {
        size_t idx = base + (size_t)j * 128;
        unsigned int re = pre[idx];
        unsigned int im = pim[idx];
        float br0 = bf2f((u16)(re & 0xffff)), br1 = bf2f((u16)(re >> 16));
        float bi0 = bf2f((u16)(im & 0xffff)), bi1 = bf2f((u16)(im >> 16));
        float nr0 = fmaf(l0.x, hr0, fmaf(-l0.y, hi0, br0));
        float ni0 = fmaf(l0.x, hi0, fmaf( l0.y, hr0, bi0));
        float nr1 = fmaf(l1.x, hr1, fmaf(-l1.y, hi1, br1));
        float ni1 = fmaf(l1.x, hi1, fmaf( l1.y, hr1, bi1));
        hr0 = nr0; hi0 = ni0; hr1 = nr1; hi1 = ni1;
        pre[idx] = ((unsigned int)f2bf(hr1) << 16) | f2bf(hr0);
        pim[idx] = ((unsigned int)f2bf(hi1) << 16) | f2bf(hi0);
    }
}

// ---------------------------------------------------------------- launch
extern "C" void kernel_launch(void* const* d_in, const int* in_sizes, int n_in,
                              void* d_out, int out_size, void* d_ws, size_t ws_size,
                              hipStream_t stream)
{
    (void)in_sizes; (void)n_in; (void)out_size; (void)ws_size;
    const float* x         = (const float*)d_in[0];
    const float* ln1_w     = (const float*)d_in[1];
    const float* ln1_b     = (const float*)d_in[2];
    const float* nu_log    = (const float*)d_in[3];
    const float* theta_log = (const float*)d_in[4];
    const float* gamma_log = (const float*)d_in[5];
    const float* B_re      = (const float*)d_in[6];
    const float* B_im      = (const float*)d_in[7];
    const float* C_re      = (const float*)d_in[8];
    const float* C_im      = (const float*)d_in[9];
    const float* Dm        = (const float*)d_in[10];
    const float* ln2_w     = (const float*)d_in[11];
    const float* ln2_b     = (const float*)d_in[12];
    const float* Wl        = (const float*)d_in[13];
    const float* bl        = (const float*)d_in[14];
    const float* Wr        = (const float*)d_in[15];
    const float* br        = (const float*)d_in[16];
    const float* ln4_w     = (const float*)d_in[17];
    const float* ln4_b     = (const float*)d_in[18];

    char* ws = (char*)d_ws;
    float* gam = (float*)(ws + OFF_GAM);
    u16* B1 = (u16*)(ws + OFF_B1);
    u16* B2 = (u16*)(ws + OFF_B2);
    u16* B3 = (u16*)(ws + OFF_B3);
    u16* u    = (u16*)(ws + OFF_BIG);
    u16* skip = (u16*)(ws + OFF_BIG + 1 * SZB);
    u16* bure = (u16*)(ws + OFF_BIG + 2 * SZB);
    u16* buim = (u16*)(ws + OFF_BIG + 3 * SZB);
    u16* y    = (u16*)(ws + OFF_BIG + 4 * SZB);
    float4* carry = (float4*)(ws + OFF_BIG + 5 * SZB);
    float* out = (float*)d_out;

    k_setup<<<dim3(256), dim3(256), 0, stream>>>(nu_log, theta_log, gamma_log,
                                                 B_re, B_im, C_re, C_im, Dm, Wl, Wr, ws);
    k_ln1<<<dim3(RR/4), dim3(256), 0, stream>>>(x, ln1_w, ln1_b, u, skip);
    k_gemm1<<<dim3(RR/128, 4), dim3(256), 0, stream>>>(u, B1, bure, buim, gam);
    k_scan1<<<dim3(BB, CH), dim3(128), 0, stream>>>(bure, buim, carry, ws);
    k_comb<<<dim3(BB), dim3(128), 0, stream>>>(carry, ws);
    k_scan2<<<dim3(BB, CH), dim3(128), 0, stream>>>(bure, buim, carry, ws);
    k_gemm2<<<dim3(RR/128), dim3(512), 0, stream>>>(bure, buim, u, B2, y, ln2_w, ln2_b);
    k_gemm3<<<dim3(RR/128, 4), dim3(256), 0, stream>>>(y, B3, bure, buim, bl, br);
    k_final<<<dim3(RR/4), dim3(256), 0, stream>>>(bure, buim, skip, ln4_w, ln4_b, out);
}